// Round 3
// baseline (229.688 us; speedup 1.0000x reference)
//
#include <hip/hip_runtime.h>
#include <hip/hip_bf16.h>

#define NB 16
#define NS 2048
#define ND 768
#define NG 1024
#define ROWS (NB * NG)            // 16384 output rows (b*G + g)

#define BM 128
#define BN 256
#define BK 32

typedef __attribute__((ext_vector_type(8))) __bf16 bf16x8;
typedef __attribute__((ext_vector_type(8))) unsigned short ushort8_t;
typedef __attribute__((ext_vector_type(4))) float f32x4;

__device__ __forceinline__ unsigned short f2bf(float f) {
    unsigned int u = __builtin_bit_cast(unsigned int, f);
    return (unsigned short)((u + 0x7FFFu + ((u >> 16) & 1u)) >> 16);   // RNE
}

__device__ __forceinline__ void gload_lds16(const void* g, void* l) {
    __builtin_amdgcn_global_load_lds((const __attribute__((address_space(1))) unsigned int*)g,
                                     (__attribute__((address_space(3))) unsigned int*)l, 16, 0, 0);
}

__device__ __forceinline__ float fast_tanh(float v) {
    float x = fminf(fmaxf(v, -15.f), 15.f);
    float e = __expf(2.f * x);
    return (e - 1.f) / (e + 1.f);
}

// ---- transpose-cast 0.5*W (768x768 f32 row-major [k][n]) to bf16 [n][k]
__global__ __launch_bounds__(256) void wtrans_kernel(const float* __restrict__ W,
                                                     unsigned short* __restrict__ Bt) {
    __shared__ float tile[64][65];
    int n0 = blockIdx.x * 64;
    int k0 = blockIdx.y * 64;
    int tx = threadIdx.x & 63;
    int ty = threadIdx.x >> 6;    // 0..3
    #pragma unroll
    for (int i = 0; i < 64; i += 4)
        tile[ty + i][tx] = W[(long)(k0 + ty + i) * ND + n0 + tx];
    __syncthreads();
    #pragma unroll
    for (int i = 0; i < 64; i += 4)
        Bt[(long)(n0 + ty + i) * ND + k0 + tx] = f2bf(0.5f * tile[tx][ty + i]);
}

// ---- fused GEMM: out[g][c] = tanh( sum_k (x[2g][k]+x[2g+1][k]) * (0.5*W)[k][c] + b[c] )
// 128x256 tile, BK=32, 4 waves (2x2), wave tile 64x128 = 4x8 frags of 16x16x32.
// A reg-staged from x (pair-add + bf16 cast); B via global_load_lds from pre-transposed Bt.
__global__ __launch_bounds__(256, 2) void gemm_fused_kernel(const float* __restrict__ x,
                                                            const unsigned short* __restrict__ Bt,
                                                            const float* __restrict__ bias,
                                                            float* __restrict__ out) {
    __shared__ unsigned short Al[BM * BK];   // [128][32]  8 KB
    __shared__ unsigned short Bl[BN * BK];   // [256][32] 16 KB (row = n, col = k)
    int tid = threadIdx.x;
    int lane = tid & 63;
    int w = tid >> 6;
    int wr = w >> 1, wc = w & 1;
    int row0 = blockIdx.y * BM;              // group rows (blockIdx.x = col strip, fastest -> A sharers concurrent)
    int col0 = blockIdx.x * BN;
    int r = lane & 15, h = lane >> 4;

    // 128 groups of this block = 256 consecutive token rows of one batch
    int b = row0 >> 10;
    long tokrow = (long)b * NS + 2 * (row0 & (NG - 1));

    // A staging: thread t -> group-row t>>1, k-half (t&1)*16 (16 floats via 4x float4 per token row)
    int ar = tid >> 1;
    int akh = (tid & 1) * 16;
    const float* ax0 = x + (tokrow + 2 * ar) * ND + akh;
    const float* ax1 = ax0 + ND;
    char* alw = (char*)Al + tid * 32;        // contiguous LDS write -> conflict-free

    // B staging: 4 x 16B chunks per thread, linear LDS
    const char* gB = (const char*)Bt + (long)(col0 + (tid >> 2)) * (ND * 2) + (tid & 3) * 16;
    char* lB = (char*)Bl + tid * 16;

    float4 a0[4], a1[4];
    #pragma unroll
    for (int j = 0; j < 4; ++j) {            // prologue: loads for k0 = 0
        a0[j] = *(const float4*)(ax0 + j * 4);
        a1[j] = *(const float4*)(ax1 + j * 4);
    }

    f32x4 acc[4][8] = {};

    for (int k0 = 0; k0 < ND; k0 += BK) {
        // write staged A (pair-sum, bf16 cast; 0.5 folded into Bt)
        ushort8_t aw0, aw1;
        #pragma unroll
        for (int e = 0; e < 4; ++e) {
            aw0[e]     = f2bf(a0[0][e] + a1[0][e]);
            aw0[4 + e] = f2bf(a0[1][e] + a1[1][e]);
            aw1[e]     = f2bf(a0[2][e] + a1[2][e]);
            aw1[4 + e] = f2bf(a0[3][e] + a1[3][e]);
        }
        *(ushort8_t*)alw = aw0;
        *(ushort8_t*)(alw + 16) = aw1;
        // B tile for this step (async -> LDS)
        #pragma unroll
        for (int q = 0; q < 4; ++q)
            gload_lds16(gB + (long)q * 64 * (ND * 2), lB + q * 4096);
        gB += BK * 2;
        __syncthreads();                     // drains B gloads + A ds_writes

        // issue NEXT step's A loads now; they fly under the MFMA phase (T14)
        int adv = (k0 + BK < ND) ? BK : 0;
        ax0 += adv; ax1 += adv;
        #pragma unroll
        for (int j = 0; j < 4; ++j) {
            a0[j] = *(const float4*)(ax0 + j * 4);
            a1[j] = *(const float4*)(ax1 + j * 4);
        }

        bf16x8 af[4];
        #pragma unroll
        for (int m = 0; m < 4; ++m)
            af[m] = __builtin_bit_cast(bf16x8, *(const ushort8_t*)&Al[(wr * 64 + m * 16 + r) * BK + h * 8]);
        #pragma unroll
        for (int n = 0; n < 8; ++n) {
            bf16x8 bfv = __builtin_bit_cast(bf16x8, *(const ushort8_t*)&Bl[(wc * 128 + n * 16 + r) * BK + h * 8]);
            #pragma unroll
            for (int m = 0; m < 4; ++m)
                acc[m][n] = __builtin_amdgcn_mfma_f32_16x16x32_bf16(af[m], bfv, acc[m][n], 0, 0, 0);
        }
        __syncthreads();
    }

    float bv[8];
    #pragma unroll
    for (int n = 0; n < 8; ++n) bv[n] = bias[col0 + wc * 128 + n * 16 + r];

    #pragma unroll
    for (int m = 0; m < 4; ++m) {
        #pragma unroll
        for (int q = 0; q < 4; ++q) {
            int orow = row0 + wr * 64 + m * 16 + h * 4 + q;
            float* op = out + (long)orow * ND + col0 + wc * 128 + r;
            #pragma unroll
            for (int n = 0; n < 8; ++n)
                op[n * 16] = fast_tanh(acc[m][n][q] + bv[n]);
        }
    }
}

// ---- per-group masks + per-block partial sums (no atomics, no pre-zero)
__global__ __launch_bounds__(256) void masks_kernel(const int* __restrict__ padding,
                                                    const int* __restrict__ regular,
                                                    const int* __restrict__ seqpair,
                                                    float* __restrict__ out_mp,
                                                    float* __restrict__ out_mr,
                                                    float* __restrict__ out_ms,
                                                    int2* __restrict__ partials) {
    int i = blockIdx.x * 256 + threadIdx.x;      // over ROWS
    int b = i >> 10, g = i & (NG - 1);
    int t = b * NS + 2 * g;
    int r0 = regular[t], r1 = regular[t + 1];
    int p  = ((padding[t] | padding[t + 1]) != 0) ? 1 : 0;
    int mr = ((r0 | r1) != 0) ? 1 : 0;
    int ms = ((seqpair[t] > 0) && (seqpair[t + 1] > 0)) ? 1 : 0;
    if (p == 0) ms = -1;
    out_mp[i] = (float)p;
    out_mr[i] = (float)mr;
    out_ms[i] = (float)ms;

    int mrs = mr, tok = r0 + r1;
    #pragma unroll
    for (int off = 32; off > 0; off >>= 1) {
        mrs += __shfl_down(mrs, off);
        tok += __shfl_down(tok, off);
    }
    __shared__ int sm[4], st[4];
    int wv = threadIdx.x >> 6, lane = threadIdx.x & 63;
    if (lane == 0) { sm[wv] = mrs; st[wv] = tok; }
    __syncthreads();
    if (threadIdx.x == 0)
        partials[blockIdx.x] = make_int2(sm[0] + sm[1] + sm[2] + sm[3],
                                         st[0] + st[1] + st[2] + st[3]);
}

// ---- compression_rate from 64 per-block partials (single wave)
__global__ void cr_kernel(const int2* __restrict__ partials, float* __restrict__ cr) {
    int2 p = partials[threadIdx.x];
    int a = p.x, t = p.y;
    #pragma unroll
    for (int off = 32; off > 0; off >>= 1) {
        a += __shfl_down(a, off);
        t += __shfl_down(t, off);
    }
    if (threadIdx.x == 0) cr[0] = (float)a / (float)t;
}

extern "C" void kernel_launch(void* const* d_in, const int* in_sizes, int n_in,
                              void* d_out, int out_size, void* d_ws, size_t ws_size,
                              hipStream_t stream) {
    const float* x        = (const float*)d_in[0];
    const int*   padding  = (const int*)d_in[2];
    const int*   regular  = (const int*)d_in[3];
    const int*   seqpair  = (const int*)d_in[4];
    const float* W        = (const float*)d_in[6];
    const float* bias     = (const float*)d_in[7];

    float* outc   = (float*)d_out;                       // compact (B,G,D)
    float* out_mp = outc + (long)ROWS * ND;              // mask_padding (B,G)
    float* out_mr = out_mp + ROWS;                       // mask_regular (B,G)
    float* out_ms = out_mr + ROWS;                       // mask_seq_pair (B,G)
    float* out_cr = out_ms + ROWS;                       // compression_rate (1)

    unsigned short* wbt = (unsigned short*)d_ws;                 // 768*768*2 = 1179648 B
    int2* partials = (int2*)((char*)d_ws + 1179648);             // 64 * 8 B

    wtrans_kernel<<<dim3(ND / 64, ND / 64), 256, 0, stream>>>(W, wbt);
    masks_kernel<<<ROWS / 256, 256, 0, stream>>>(padding, regular, seqpair, out_mp, out_mr, out_ms, partials);
    gemm_fused_kernel<<<dim3(ND / BN, ROWS / BM), 256, 0, stream>>>(x, wbt, bias, outc);
    cr_kernel<<<1, 64, 0, stream>>>(partials, out_cr);
}

// Round 4
// 206.629 us; speedup vs baseline: 1.1116x; 1.1116x over previous
//
#include <hip/hip_runtime.h>
#include <hip/hip_bf16.h>

#define NB 16
#define NS 2048
#define ND 768
#define NG 1024
#define ROWS (NB * NG)            // 16384 output rows (b*G + g)

#define BM 64
#define BN 256
#define BK 32
#define NCOL (ND / BN)            // 3 col-strips
#define NROW (ROWS / BM)          // 256 row-bands

typedef __attribute__((ext_vector_type(8))) __bf16 bf16x8;
typedef __attribute__((ext_vector_type(8))) unsigned short ushort8_t;
typedef __attribute__((ext_vector_type(4))) float f32x4;

__device__ __forceinline__ unsigned short f2bf(float f) {
    unsigned int u = __builtin_bit_cast(unsigned int, f);
    return (unsigned short)((u + 0x7FFFu + ((u >> 16) & 1u)) >> 16);   // RNE
}

__device__ __forceinline__ void gload_lds16(const void* g, void* l) {
    __builtin_amdgcn_global_load_lds((const __attribute__((address_space(1))) unsigned int*)g,
                                     (__attribute__((address_space(3))) unsigned int*)l, 16, 0, 0);
}

__device__ __forceinline__ float fast_tanh(float v) {
    float x = fminf(fmaxf(v, -15.f), 15.f);
    float e = __expf(2.f * x);
    return (e - 1.f) / (e + 1.f);
}

// ---- transpose-cast 0.5*W (768x768 f32 row-major [k][n]) to bf16 [n][k]
__global__ __launch_bounds__(256) void wtrans_kernel(const float* __restrict__ W,
                                                     unsigned short* __restrict__ Bt) {
    __shared__ float tile[64][65];
    int n0 = blockIdx.x * 64;
    int k0 = blockIdx.y * 64;
    int tx = threadIdx.x & 63;
    int ty = threadIdx.x >> 6;    // 0..3
    #pragma unroll
    for (int i = 0; i < 64; i += 4)
        tile[ty + i][tx] = W[(long)(k0 + ty + i) * ND + n0 + tx];
    __syncthreads();
    #pragma unroll
    for (int i = 0; i < 64; i += 4)
        Bt[(long)(n0 + ty + i) * ND + k0 + tx] = f2bf(0.5f * tile[tx][ty + i]);
}

// ---- fused GEMM: out[g][c] = tanh( sum_k (x[2g][k]+x[2g+1][k]) * (0.5*W)[k][c] + b[c] )
// BM=64 groups x BN=256 cols, BK=32; 4 waves (2x2), wave tile 32x128 = 2x8 frags.
// Grid 768 = 3 blocks/CU. XCD swizzle: row-band's 3 col-strips consecutive on one XCD.
__global__ __launch_bounds__(256, 3) void gemm_fused_kernel(const float* __restrict__ x,
                                                            const unsigned short* __restrict__ Bt,
                                                            const float* __restrict__ bias,
                                                            float* __restrict__ out) {
    __shared__ unsigned short Al[BM * BK];   // [64][32]   4 KB
    __shared__ unsigned short Bl[BN * BK];   // [256][32] 16 KB (row = n, col = k)
    int tid = threadIdx.x;
    int lane = tid & 63;
    int w = tid >> 6;
    int wr = w >> 1, wc = w & 1;

    // bijective XCD swizzle: xcd = bid&7 gets bands {xcd, xcd+8, ...}, 3 col-strips each
    int bid = blockIdx.x;                    // 0..767
    int xcd = bid & 7;
    int s = bid >> 3;                        // 0..95
    int c = s % 3;
    int rb = (s / 3) * 8 + xcd;              // 0..255
    int row0 = rb * BM;
    int col0 = c * BN;
    int r = lane & 15, h = lane >> 4;

    int b = row0 >> 10;
    long tokrow = (long)b * NS + 2 * (row0 & (NG - 1));

    // A staging: thread t -> group g=t>>2, k-quarter q=t&3 (8 k f32 of both tokens)
    const float* ax0 = x + (tokrow + 2 * (tid >> 2)) * ND + (tid & 3) * 8;
    const float* ax1 = ax0 + ND;
    char* alw = (char*)Al + tid * 16;        // contiguous 16B/thread -> conflict-free

    // B staging: 4 x 16B chunks per thread, linear LDS
    const char* gB = (const char*)Bt + (long)(col0 + (tid >> 2)) * (ND * 2) + (tid & 3) * 16;
    char* lB = (char*)Bl + tid * 16;

    float4 a0[2], a1[2];
    #pragma unroll
    for (int j = 0; j < 2; ++j) {            // prologue loads for k0 = 0
        a0[j] = *(const float4*)(ax0 + j * 4);
        a1[j] = *(const float4*)(ax1 + j * 4);
    }

    f32x4 acc[2][8] = {};

    for (int k0 = 0; k0 < ND; k0 += BK) {
        ushort8_t aw;
        #pragma unroll
        for (int e = 0; e < 4; ++e) {
            aw[e]     = f2bf(a0[0][e] + a1[0][e]);
            aw[4 + e] = f2bf(a0[1][e] + a1[1][e]);
        }
        *(ushort8_t*)alw = aw;
        #pragma unroll
        for (int q = 0; q < 4; ++q)
            gload_lds16(gB + (long)q * 64 * (ND * 2), lB + q * 4096);
        gB += BK * 2;
        __syncthreads();                     // drains B gloads + A ds_writes

        // issue NEXT step's A loads now; they fly under the MFMA phase (T14)
        int adv = (k0 + BK < ND) ? BK : 0;
        ax0 += adv; ax1 += adv;
        #pragma unroll
        for (int j = 0; j < 2; ++j) {
            a0[j] = *(const float4*)(ax0 + j * 4);
            a1[j] = *(const float4*)(ax1 + j * 4);
        }

        bf16x8 af[2];
        #pragma unroll
        for (int m = 0; m < 2; ++m)
            af[m] = __builtin_bit_cast(bf16x8, *(const ushort8_t*)&Al[(wr * 32 + m * 16 + r) * BK + h * 8]);
        #pragma unroll
        for (int n = 0; n < 8; ++n) {
            bf16x8 bfv = __builtin_bit_cast(bf16x8, *(const ushort8_t*)&Bl[(wc * 128 + n * 16 + r) * BK + h * 8]);
            #pragma unroll
            for (int m = 0; m < 2; ++m)
                acc[m][n] = __builtin_amdgcn_mfma_f32_16x16x32_bf16(af[m], bfv, acc[m][n], 0, 0, 0);
        }
        __syncthreads();
    }

    float bv[8];
    #pragma unroll
    for (int n = 0; n < 8; ++n) bv[n] = bias[col0 + wc * 128 + n * 16 + r];

    #pragma unroll
    for (int m = 0; m < 2; ++m) {
        #pragma unroll
        for (int q = 0; q < 4; ++q) {
            int orow = row0 + wr * 32 + m * 16 + h * 4 + q;
            float* op = out + (long)orow * ND + col0 + wc * 128 + r;
            #pragma unroll
            for (int n = 0; n < 8; ++n)
                op[n * 16] = fast_tanh(acc[m][n][q] + bv[n]);
        }
    }
}

// ---- per-group masks + per-block partial sums (no atomics, no pre-zero)
__global__ __launch_bounds__(256) void masks_kernel(const int* __restrict__ padding,
                                                    const int* __restrict__ regular,
                                                    const int* __restrict__ seqpair,
                                                    float* __restrict__ out_mp,
                                                    float* __restrict__ out_mr,
                                                    float* __restrict__ out_ms,
                                                    int2* __restrict__ partials) {
    int i = blockIdx.x * 256 + threadIdx.x;      // over ROWS
    int b = i >> 10, g = i & (NG - 1);
    int t = b * NS + 2 * g;
    int r0 = regular[t], r1 = regular[t + 1];
    int p  = ((padding[t] | padding[t + 1]) != 0) ? 1 : 0;
    int mr = ((r0 | r1) != 0) ? 1 : 0;
    int ms = ((seqpair[t] > 0) && (seqpair[t + 1] > 0)) ? 1 : 0;
    if (p == 0) ms = -1;
    out_mp[i] = (float)p;
    out_mr[i] = (float)mr;
    out_ms[i] = (float)ms;

    int mrs = mr, tok = r0 + r1;
    #pragma unroll
    for (int off = 32; off > 0; off >>= 1) {
        mrs += __shfl_down(mrs, off);
        tok += __shfl_down(tok, off);
    }
    __shared__ int sm[4], st[4];
    int wv = threadIdx.x >> 6, lane = threadIdx.x & 63;
    if (lane == 0) { sm[wv] = mrs; st[wv] = tok; }
    __syncthreads();
    if (threadIdx.x == 0)
        partials[blockIdx.x] = make_int2(sm[0] + sm[1] + sm[2] + sm[3],
                                         st[0] + st[1] + st[2] + st[3]);
}

// ---- compression_rate from 64 per-block partials (single wave)
__global__ void cr_kernel(const int2* __restrict__ partials, float* __restrict__ cr) {
    int2 p = partials[threadIdx.x];
    int a = p.x, t = p.y;
    #pragma unroll
    for (int off = 32; off > 0; off >>= 1) {
        a += __shfl_down(a, off);
        t += __shfl_down(t, off);
    }
    if (threadIdx.x == 0) cr[0] = (float)a / (float)t;
}

extern "C" void kernel_launch(void* const* d_in, const int* in_sizes, int n_in,
                              void* d_out, int out_size, void* d_ws, size_t ws_size,
                              hipStream_t stream) {
    const float* x        = (const float*)d_in[0];
    const int*   padding  = (const int*)d_in[2];
    const int*   regular  = (const int*)d_in[3];
    const int*   seqpair  = (const int*)d_in[4];
    const float* W        = (const float*)d_in[6];
    const float* bias     = (const float*)d_in[7];

    float* outc   = (float*)d_out;                       // compact (B,G,D)
    float* out_mp = outc + (long)ROWS * ND;              // mask_padding (B,G)
    float* out_mr = out_mp + ROWS;                       // mask_regular (B,G)
    float* out_ms = out_mr + ROWS;                       // mask_seq_pair (B,G)
    float* out_cr = out_ms + ROWS;                       // compression_rate (1)

    unsigned short* wbt = (unsigned short*)d_ws;                 // 768*768*2 = 1179648 B
    int2* partials = (int2*)((char*)d_ws + 1179648);             // 64 * 8 B

    wtrans_kernel<<<dim3(ND / 64, ND / 64), 256, 0, stream>>>(W, wbt);
    masks_kernel<<<ROWS / 256, 256, 0, stream>>>(padding, regular, seqpair, out_mp, out_mr, out_ms, partials);
    gemm_fused_kernel<<<NCOL * NROW, 256, 0, stream>>>(x, wbt, bias, outc);
    cr_kernel<<<1, 64, 0, stream>>>(partials, out_cr);
}